// Round 5
// baseline (32597.986 us; speedup 1.0000x reference)
//
#include <hip/hip_runtime.h>
#include <stdint.h>
#include <math.h>

typedef _Float16 f16;
typedef __attribute__((ext_vector_type(8))) _Float16 f16x8;
typedef __attribute__((ext_vector_type(4))) float f32x4;
typedef unsigned long long u64;

__device__ __forceinline__ float sigm(float x){ return 1.0f/(1.0f + expf(-x)); }

// nontemporal f16x8 load (streaming data: keep W resident in L2)
__device__ __forceinline__ f16x8 ntld(const f16* p){
  return __builtin_nontemporal_load((const f16x8*)p);
}

// ---------------- split fp32 -> (hi fp16, lo fp16 scaled by 2048) ----------------
__global__ __launch_bounds__(256) void split_w(const float* __restrict__ src,
                                               f16* __restrict__ hi, f16* __restrict__ lo, int n){
  int i = blockIdx.x*256 + threadIdx.x;
  if (i >= n) return;
  float x = src[i];
  f16 h = (f16)x;
  float r = x - (float)h;
  hi[i] = h;
  lo[i] = (f16)(r * 2048.0f);
}

// ---------------- token tables: table[v][3H] = emb[v] @ Wih^T + bih (fp32) ----------------
__global__ __launch_bounds__(256) void build_tables(
    const float* __restrict__ emb,
    const float* __restrict__ encWih, const float* __restrict__ encBih,
    const float* __restrict__ decWih, const float* __restrict__ decBih,
    float* __restrict__ tabE, float* __restrict__ tabD)
{
  __shared__ float se[256];
  int v = blockIdx.y;
  int col = blockIdx.x*256 + threadIdx.x;
  const float* W  = blockIdx.z ? decWih : encWih;
  const float* bi = blockIdx.z ? decBih : encBih;
  float* tab      = blockIdx.z ? tabD   : tabE;
  se[threadIdx.x] = emb[v*256 + threadIdx.x];
  __syncthreads();
  const float* wr = W + (size_t)col*256;
  float s = 0.f;
  #pragma unroll 8
  for (int k = 0; k < 256; ++k) s += se[k]*wr[k];
  tab[(size_t)v*3072 + col] = s + bi[col];
}

// ---------------- fused GRU step: B via LDS (double-buffered), A direct-from-global ----------
// 256 blocks x 256 threads, 1 block/CU. Tile 64 rows x 192 cols (3 gates x 64), BK=64.
// LDS 96 KiB: sB[2buf][2limb][192r x 8 slots of 16B], XOR slot swizzle -> conflict-free reads.
// A (h limbs) loaded nontemporal straight into MFMA fragments, prefetched 1 chunk ahead
// in two register banks (all compile-time indexed). Streaming h in/out is nt so the
// per-XCD W col-slice (1.5 MB) stays L2-resident across all 256 timesteps.
template<int DEC>
__global__ __launch_bounds__(256, 1) void gru_kernel(
    const f16* __restrict__ hHi, const f16* __restrict__ hLo, const float* __restrict__ hOldF,
    const f16* __restrict__ WHi, const f16* __restrict__ WLo,
    const float* __restrict__ bhh, const float* __restrict__ table,
    const int* __restrict__ x, const u64* __restrict__ tokPrev, int t,
    float* __restrict__ hNewF, f16* __restrict__ hNewHi, f16* __restrict__ hNewLo)
{
  __shared__ f16x8 sB[2][2][1536];   // 96 KiB

  // XCD swizzle (round-robin assumption): each XCD owns 2 col-slices x 16 row-blocks
  const int raw = blockIdx.x;
  const int j = raw >> 3;
  const int colBlk = (raw & 7)*2 + (j >> 4);   // 0..15, 64 cols each
  const int rowBlk = j & 15;                   // 0..15, 64 rows each

  const int tid  = threadIdx.x;
  const int lane = tid & 63;
  const int wave = tid >> 6;
  const int quad = lane >> 4, lid = lane & 15;
  const int rbase = (wave>>1)*32;   // block-local row base of this wave
  const int cbase = (wave&1)*32;    // within-gate col base of this wave

  f32x4 accH[3][2][2] = {};
  f32x4 accX[3][2][2] = {};

  // ---- B staging descriptors: 6 slots per thread, each one f16x8 (16B) ----
  int gbOf[6], lbOf[6];
  #pragma unroll
  for (int i = 0; i < 6; ++i){
    int s = tid + 256*i, brow = s >> 3, kk = s & 7;
    gbOf[i] = ((brow>>6)*1024 + colBlk*64 + (brow & 63))*1024 + kk*8;
    lbOf[i] = brow*8 + (kk ^ (brow & 7));
  }

  // ---- A fragment global offsets (per rt), values identical to R4's LDS path ----
  int aOf[2];
  #pragma unroll
  for (int rt = 0; rt < 2; ++rt)
    aOf[rt] = (rowBlk*64 + rbase + rt*16 + lid)*1024 + quad*8;

  f16x8 stg[12];
#define BGLOAD(CK) do{ int k0 = (CK)*64; \
    _Pragma("unroll") for (int i = 0; i < 6; ++i){ \
      stg[i]   = *(const f16x8*)(WHi + gbOf[i] + k0); \
      stg[6+i] = *(const f16x8*)(WLo + gbOf[i] + k0); } }while(0)

#define BSWRITE(BUF) do{ \
    _Pragma("unroll") for (int i = 0; i < 6; ++i){ \
      sB[BUF][0][lbOf[i]] = stg[i]; sB[BUF][1][lbOf[i]] = stg[6+i]; } }while(0)

#define ALOAD(DST, CK) do{ int k0 = (CK)*64; \
    _Pragma("unroll") for (int ks = 0; ks < 2; ++ks) \
      _Pragma("unroll") for (int rt = 0; rt < 2; ++rt){ \
        DST[ks][0][rt] = ntld(hHi + aOf[rt] + k0 + ks*32); \
        DST[ks][1][rt] = ntld(hLo + aOf[rt] + k0 + ks*32); } }while(0)

#define COMPUTE(BUF, AC) do{ \
    _Pragma("unroll") for (int ksub = 0; ksub < 2; ++ksub){ \
      const int kq = ksub*4 + quad; \
      f16x8 bH[3][2], bL[3][2]; \
      _Pragma("unroll") for (int g = 0; g < 3; ++g) \
        _Pragma("unroll") for (int ct = 0; ct < 2; ++ct){ \
          int bl = g*64 + cbase + ct*16 + lid; \
          int off = bl*8 + (kq ^ (bl & 7)); \
          bH[g][ct] = sB[BUF][0][off]; \
          bL[g][ct] = sB[BUF][1][off]; } \
      _Pragma("unroll") for (int g = 0; g < 3; ++g) \
        _Pragma("unroll") for (int rt = 0; rt < 2; ++rt) \
          _Pragma("unroll") for (int ct = 0; ct < 2; ++ct){ \
            accH[g][rt][ct] = __builtin_amdgcn_mfma_f32_16x16x32_f16(AC[ksub][0][rt], bH[g][ct], accH[g][rt][ct], 0,0,0); \
            accX[g][rt][ct] = __builtin_amdgcn_mfma_f32_16x16x32_f16(AC[ksub][0][rt], bL[g][ct], accX[g][rt][ct], 0,0,0); \
            accX[g][rt][ct] = __builtin_amdgcn_mfma_f32_16x16x32_f16(AC[ksub][1][rt], bH[g][ct], accX[g][rt][ct], 0,0,0); } \
    } }while(0)

  f16x8 aP[2][2][2], aQ[2][2][2];   // [ksub][limb][rt], two chunk banks

  // prologue
  BGLOAD(0);
  BSWRITE(0);
  ALOAD(aP, 0);
  __syncthreads();
  BGLOAD(1);

  // steady state: 16 chunks, unrolled by 2 (A banks alternate, compile-time indices)
  for (int ck2 = 0; ck2 < 16; ck2 += 2){
    // chunk ck2 (buf 0)
    ALOAD(aQ, ck2+1);
    COMPUTE(0, aP);
    BSWRITE(1);
    if (ck2 < 14) BGLOAD(ck2+2);
    __syncthreads();
    // chunk ck2+1 (buf 1)
    if (ck2 < 14) ALOAD(aP, ck2+2);
    COMPUTE(1, aQ);
    if (ck2 < 14) BSWRITE(0);
    if (ck2 < 13) BGLOAD(ck2+3);
    __syncthreads();
  }
#undef BGLOAD
#undef BSWRITE
#undef ALOAD
#undef COMPUTE

  const float s = 1.0f/2048.0f;
  #pragma unroll
  for (int rt = 0; rt < 2; ++rt){
    #pragma unroll
    for (int r = 0; r < 4; ++r){
      int row = rowBlk*64 + rbase + rt*16 + quad*4 + r;
      int tk;
      if (DEC) tk = (t == 0) ? 0 : (255 - (int)(tokPrev[row] & 255));
      else     tk = x[(size_t)row*256 + t] & 255;
      const float* trow = table + (size_t)tk*3072;
      #pragma unroll
      for (int ct = 0; ct < 2; ++ct){
        int col = colBlk*64 + cbase + ct*16 + lid;
        float Cr = accH[0][rt][ct][r] + accX[0][rt][ct][r]*s + bhh[col];
        float Cz = accH[1][rt][ct][r] + accX[1][rt][ct][r]*s + bhh[1024+col];
        float Cn = accH[2][rt][ct][r] + accX[2][rt][ct][r]*s + bhh[2048+col];
        float rg = sigm(trow[col] + Cr);
        float zg = sigm(trow[1024+col] + Cz);
        float ng = tanhf(trow[2048+col] + rg*Cn);
        size_t o = (size_t)row*1024 + col;
        float hv = (1.0f - zg)*ng + zg*__builtin_nontemporal_load(hOldF + o);
        __builtin_nontemporal_store(hv, hNewF + o);
        f16 hi = (f16)hv;
        float rr2 = hv - (float)hi;
        __builtin_nontemporal_store(hi, hNewHi + o);
        __builtin_nontemporal_store((f16)(rr2 * 2048.0f), hNewLo + o);
      }
    }
  }
}

// ---------------- logits: 256 blocks x (16 rows x 64 cols); packed-u64 atomic argmax --------
// key = (order-preserving-u32(value) << 8) | (255 - col): max => max value, lowest col on ties
__device__ __forceinline__ u64 akey(float v, int gcol){
  unsigned int b = __float_as_uint(v);
  unsigned int u = (b & 0x80000000u) ? ~b : (b | 0x80000000u);
  return ((u64)u << 8) | (unsigned)(255 - gcol);
}

__global__ __launch_bounds__(256) void logits_argmax(
    const f16* __restrict__ hHi, const f16* __restrict__ hLo,
    const f16* __restrict__ oWHi, const f16* __restrict__ oWLo,
    const float* __restrict__ outB,
    float* __restrict__ outRecon, int t,
    u64* __restrict__ tokCur, u64* __restrict__ tokNext)
{
  __shared__ float lds[16][64];
  const int lane = threadIdx.x & 63;
  const int wave = threadIdx.x >> 6;
  const int quad = lane >> 4, lid = lane & 15;
  const int rowBase = (blockIdx.x >> 2) * 16;
  const int cgrp = blockIdx.x & 3;
  if (cgrp == 0 && threadIdx.x < 16) tokNext[rowBase + threadIdx.x] = 0ull; // reset t+1 buffer
  const int colBase = cgrp*64 + wave*16;

  f32x4 accH = {}, accX = {};
  for (int k0 = 0; k0 < 1024; k0 += 32){
    size_t aoff = (size_t)(rowBase + lid)*1024 + k0 + quad*8;
    f16x8 aH = ntld(hHi + aoff);
    f16x8 aL = ntld(hLo + aoff);
    size_t boff = (size_t)(colBase + lid)*1024 + k0 + quad*8;
    f16x8 bH = *(const f16x8*)(oWHi + boff);
    f16x8 bL = *(const f16x8*)(oWLo + boff);
    accH = __builtin_amdgcn_mfma_f32_16x16x32_f16(aH, bH, accH, 0,0,0);
    accX = __builtin_amdgcn_mfma_f32_16x16x32_f16(aH, bL, accX, 0,0,0);
    accX = __builtin_amdgcn_mfma_f32_16x16x32_f16(aL, bH, accX, 0,0,0);
  }
  const float sc = 1.0f/2048.0f;
  const int col = colBase + lid;
  #pragma unroll
  for (int r = 0; r < 4; ++r){
    int rl = quad*4 + r;
    float v = accH[r] + accX[r]*sc + outB[col];
    lds[rl][col - cgrp*64] = v;
    __builtin_nontemporal_store(v, outRecon + (size_t)(rowBase + rl)*65536 + (size_t)t*256 + col);
  }
  __syncthreads();
  // wave w reduces rows w*4..w*4+3 over this block's 64 cols, then one atomic per row
  #pragma unroll
  for (int rr = 0; rr < 4; ++rr){
    int rl = wave*4 + rr;
    u64 k = akey(lds[rl][lane], cgrp*64 + lane);
    for (int off = 32; off >= 1; off >>= 1){
      u64 o = __shfl_down(k, off, 64);
      if (o > k) k = o;
    }
    if (lane == 0) atomicMax(tokCur + rowBase + rl, k);
  }
}

// ---------------- latent A: mu, logvar, z ----------------
__global__ __launch_bounds__(256) void latent_a(
    const float* __restrict__ hT,
    const float* __restrict__ muW, const float* __restrict__ muB,
    const float* __restrict__ lvW, const float* __restrict__ lvB,
    const float* __restrict__ eps,
    float* __restrict__ outMu, float* __restrict__ outLv,
    float* __restrict__ z)
{
  __shared__ float sh[1024];
  int b = blockIdx.x, l = threadIdx.x;
  for (int i = l; i < 1024; i += 256) sh[i] = hT[(size_t)b*1024 + i];
  __syncthreads();
  const float* mw = muW + (size_t)l*1024;
  const float* lw = lvW + (size_t)l*1024;
  float sm = 0.f, sv = 0.f;
  #pragma unroll 8
  for (int k = 0; k < 1024; ++k){ float h = sh[k]; sm += h*mw[k]; sv += h*lw[k]; }
  sm += muB[l]; sv += lvB[l];
  float zz = sm + eps[(size_t)b*256 + l] * expf(0.5f*sv);
  outMu[(size_t)b*256 + l] = sm;
  outLv[(size_t)b*256 + l] = sv;
  z[(size_t)b*256 + l] = zz;
}

// ---------------- latent B: h0_dec = tanh(z @ l2h^T + b) ----------------
__global__ __launch_bounds__(256) void latent_b(
    const float* __restrict__ z,
    const float* __restrict__ l2hW, const float* __restrict__ l2hB,
    float* __restrict__ hF, f16* __restrict__ hHi, f16* __restrict__ hLo)
{
  __shared__ float sz[256];
  int b = blockIdx.x;
  int jj = blockIdx.y*256 + threadIdx.x;
  sz[threadIdx.x] = z[(size_t)b*256 + threadIdx.x];
  __syncthreads();
  const float* wr = l2hW + (size_t)jj*256;
  float s = 0.f;
  #pragma unroll 8
  for (int k = 0; k < 256; ++k) s += sz[k]*wr[k];
  float h = tanhf(s + l2hB[jj]);
  size_t o = (size_t)b*1024 + jj;
  hF[o] = h;
  f16 hi = (f16)h;
  float r = h - (float)hi;
  hHi[o] = hi;
  hLo[o] = (f16)(r * 2048.0f);
}

extern "C" void kernel_launch(void* const* d_in, const int* in_sizes, int n_in,
                              void* d_out, int out_size, void* d_ws, size_t ws_size,
                              hipStream_t stream) {
  const int*   x      = (const int*)d_in[0];
  const float* eps    = (const float*)d_in[1];
  const float* emb    = (const float*)d_in[2];
  const float* encWih = (const float*)d_in[3];
  const float* encWhh = (const float*)d_in[4];
  const float* encBih = (const float*)d_in[5];
  const float* encBhh = (const float*)d_in[6];
  const float* muW    = (const float*)d_in[7];
  const float* muB    = (const float*)d_in[8];
  const float* lvW    = (const float*)d_in[9];
  const float* lvB    = (const float*)d_in[10];
  const float* l2hW   = (const float*)d_in[11];
  const float* l2hB   = (const float*)d_in[12];
  const float* decWih = (const float*)d_in[13];
  const float* decWhh = (const float*)d_in[14];
  const float* decBih = (const float*)d_in[15];
  const float* decBhh = (const float*)d_in[16];
  const float* outW   = (const float*)d_in[17];
  const float* outB   = (const float*)d_in[18];

  // ---- outputs (fp32) ----
  float* outRecon = (float*)d_out;               // [1024][256][256]
  float* outMu    = outRecon + 67108864;         // [1024][256]
  float* outLv    = outMu + 262144;

  // ---- encoder-phase scratch inside d_out recon region (dead until decode) ----
  char* ob = (char*)d_out;
  float* tabE   = (float*)(ob + 0);              // 3 MB
  f16*   eWHi   = (f16*)(ob + 3145728);          // 6 MB
  f16*   eWLo   = (f16*)(ob + 9437184);          // 6 MB
  float* zbuf   = (float*)(ob + 15728640);       // 1 MB

  // ---- decoder-persistent scratch in ws ----
  char* ws = (char*)d_ws;
  float* tabD   = (float*)(ws + 0);              // 3 MB
  f16*   dWHi   = (f16*)(ws + 3145728);          // 6 MB
  f16*   dWLo   = (f16*)(ws + 9437184);          // 6 MB
  f16*   oWHi   = (f16*)(ws + 15728640);         // 0.5 MB
  f16*   oWLo   = (f16*)(ws + 16252928);         // 0.5 MB
  float* hF[2]  = { (float*)(ws + 16777216), (float*)(ws + 25165824) };
  f16*   hHi[2] = { (f16*)(ws + 20971520),   (f16*)(ws + 29360128) };
  f16*   hLo[2] = { (f16*)(ws + 23068672),   (f16*)(ws + 31457280) };
  u64*   tokb[2]= { (u64*)(ws + 33554432),   (u64*)(ws + 33562624) };  // 8 KB each

  // weight limb splits
  split_w<<<12288, 256, 0, stream>>>(encWhh, eWHi, eWLo, 3145728);
  split_w<<<12288, 256, 0, stream>>>(decWhh, dWHi, dWLo, 3145728);
  split_w<<<1024, 256, 0, stream>>>(outW, oWHi, oWLo, 262144);

  // token->gi tables (fp32)
  build_tables<<<dim3(12,256,2), 256, 0, stream>>>(emb, encWih, encBih, decWih, decBih, tabE, tabD);

  // zero encoder h0 (hF0 + hHi0 + hLo0 contiguous, 8 MB) and token argmax buffers
  hipMemsetAsync(ws + 16777216, 0, 8388608, stream);
  hipMemsetAsync(ws + 33554432, 0, 16384, stream);

  // ---- encoder: 256 GRU steps, ping-pong ----
  for (int t = 0; t < 256; ++t){
    int a = t & 1, b = a ^ 1;
    gru_kernel<0><<<256, 256, 0, stream>>>(
        hHi[a], hLo[a], hF[a], eWHi, eWLo, encBhh, tabE, x, nullptr, t,
        hF[b], hHi[b], hLo[b]);
  }
  // hT in buffer 0

  // ---- latent ----
  latent_a<<<1024, 256, 0, stream>>>(hF[0], muW, muB, lvW, lvB, eps, outMu, outLv, zbuf);
  latent_b<<<dim3(1024,4), 256, 0, stream>>>(zbuf, l2hW, l2hB, hF[0], hHi[0], hLo[0]);

  // ---- decoder: 256 x (GRU step + logits/argmax) ----
  for (int t = 0; t < 256; ++t){
    int a = t & 1, b = a ^ 1;
    gru_kernel<1><<<256, 256, 0, stream>>>(
        hHi[a], hLo[a], hF[a], dWHi, dWLo, decBhh, tabD, nullptr, tokb[(t+1)&1], t,
        hF[b], hHi[b], hLo[b]);
    logits_argmax<<<256, 256, 0, stream>>>(
        hHi[b], hLo[b], oWHi, oWLo, outB, outRecon, t, tokb[t&1], tokb[(t+1)&1]);
  }
  (void)in_sizes; (void)n_in; (void)out_size; (void)ws_size;
}

// Round 6
// 19691.806 us; speedup vs baseline: 1.6554x; 1.6554x over previous
//
#include <hip/hip_runtime.h>
#include <stdint.h>
#include <math.h>

typedef _Float16 f16;
typedef __attribute__((ext_vector_type(8))) _Float16 f16x8;
typedef __attribute__((ext_vector_type(4))) float f32x4;
typedef unsigned long long u64;

__device__ __forceinline__ float sigm(float x){ return 1.0f/(1.0f + expf(-x)); }

// ---------------- split fp32 -> (hi fp16, lo fp16 scaled by 2048) ----------------
__global__ __launch_bounds__(256) void split_w(const float* __restrict__ src,
                                               f16* __restrict__ hi, f16* __restrict__ lo, int n){
  int i = blockIdx.x*256 + threadIdx.x;
  if (i >= n) return;
  float x = src[i];
  f16 h = (f16)x;
  float r = x - (float)h;
  hi[i] = h;
  lo[i] = (f16)(r * 2048.0f);
}

// ---------------- token tables: table[v][3H] = emb[v] @ Wih^T + bih (fp32) ----------------
__global__ __launch_bounds__(256) void build_tables(
    const float* __restrict__ emb,
    const float* __restrict__ encWih, const float* __restrict__ encBih,
    const float* __restrict__ decWih, const float* __restrict__ decBih,
    float* __restrict__ tabE, float* __restrict__ tabD)
{
  __shared__ float se[256];
  int v = blockIdx.y;
  int col = blockIdx.x*256 + threadIdx.x;
  const float* W  = blockIdx.z ? decWih : encWih;
  const float* bi = blockIdx.z ? decBih : encBih;
  float* tab      = blockIdx.z ? tabD   : tabE;
  se[threadIdx.x] = emb[v*256 + threadIdx.x];
  __syncthreads();
  const float* wr = W + (size_t)col*256;
  float s = 0.f;
  #pragma unroll 8
  for (int k = 0; k < 256; ++k) s += se[k]*wr[k];
  tab[(size_t)v*3072 + col] = s + bi[col];
}

// ---------------- fused GRU step: LDS-tiled, double-buffered, 8 waves (2/SIMD) ----------
// 256 blocks x 512 threads, 1 block/CU. Tile 64 rows x 192 cols (3 gates x 64), BK=64.
// Same LDS layout/traffic and same per-element K-accumulation order as the R4 kernel
// (bitwise-identical output); only the wave partition changed: 8 waves = 2 rowGroups x
// 4 colGroups (16 within-gate cols each) -> 2 waves/SIMD so ds ops of one wave overlap
// MFMAs of the other. Staging halves to 8 f16x8 slots/thread.
template<int DEC>
__global__ __launch_bounds__(512, 1) void gru_kernel(
    const f16* __restrict__ hHi, const f16* __restrict__ hLo, const float* __restrict__ hOldF,
    const f16* __restrict__ WHi, const f16* __restrict__ WLo,
    const float* __restrict__ bhh, const float* __restrict__ table,
    const int* __restrict__ x, const u64* __restrict__ tokPrev, int t,
    float* __restrict__ hNewF, f16* __restrict__ hNewHi, f16* __restrict__ hNewLo)
{
  __shared__ f16x8 sA[2][2][512];    // 32 KiB: 64 rows x 8 k-slots
  __shared__ f16x8 sB[2][2][1536];   // 96 KiB: 192 rows x 8 k-slots

  // XCD swizzle (round-robin assumption): each XCD owns 2 col-slices x 16 row-blocks
  const int raw = blockIdx.x;
  const int j = raw >> 3;
  const int colBlk = (raw & 7)*2 + (j >> 4);   // 0..15, 64 cols each
  const int rowBlk = j & 15;                   // 0..15, 64 rows each

  const int tid  = threadIdx.x;
  const int lane = tid & 63;
  const int wave = tid >> 6;        // 0..7
  const int quad = lane >> 4, lid = lane & 15;
  const int rbase = (wave>>2)*32;   // 2 row groups of 32
  const int cbase = (wave&3)*16;    // 4 col groups of 16 (within-gate)

  f32x4 accH[3][2] = {};   // [gate][rt]
  f32x4 accX[3][2] = {};

  // ---- staging descriptors: 1 A-slot + 3 B-slots per thread (each f16x8, both limbs) ----
  int gaOf, laOf, gbOf[3], lbOf[3];
  {
    int s = tid, row = s >> 3, kk = s & 7;
    gaOf = (rowBlk*64 + row)*1024 + kk*8;
    laOf = row*8 + (kk ^ (row & 7));
  }
  #pragma unroll
  for (int i = 0; i < 3; ++i){
    int s = tid + 512*i, brow = s >> 3, kk = s & 7;
    gbOf[i] = ((brow>>6)*1024 + colBlk*64 + (brow & 63))*1024 + kk*8;
    lbOf[i] = brow*8 + (kk ^ (brow & 7));
  }

  f16x8 stg[8];
#define GLOAD(CK) do{ int k0 = (CK)*64; \
    stg[0] = *(const f16x8*)(hHi + gaOf + k0); \
    stg[1] = *(const f16x8*)(hLo + gaOf + k0); \
    _Pragma("unroll") for (int i = 0; i < 3; ++i){ \
      stg[2+i] = *(const f16x8*)(WHi + gbOf[i] + k0); \
      stg[5+i] = *(const f16x8*)(WLo + gbOf[i] + k0); } }while(0)

#define SWRITE(BUF) do{ \
    sA[BUF][0][laOf] = stg[0]; sA[BUF][1][laOf] = stg[1]; \
    _Pragma("unroll") for (int i = 0; i < 3; ++i){ \
      sB[BUF][0][lbOf[i]] = stg[2+i]; sB[BUF][1][lbOf[i]] = stg[5+i]; } }while(0)

  GLOAD(0);
  SWRITE(0);
  __syncthreads();
  GLOAD(1);

  for (int ck = 0; ck < 16; ++ck){
    const int buf = ck & 1;
    #pragma unroll
    for (int ksub = 0; ksub < 2; ++ksub){
      const int kq = ksub*4 + quad;
      f16x8 aH[2], aL[2];
      #pragma unroll
      for (int rt = 0; rt < 2; ++rt){
        int rl = rbase + rt*16 + lid;
        int off = rl*8 + (kq ^ (rl & 7));
        aH[rt] = sA[buf][0][off];
        aL[rt] = sA[buf][1][off];
      }
      f16x8 bH[3], bL[3];
      #pragma unroll
      for (int g = 0; g < 3; ++g){
        int bl = g*64 + cbase + lid;
        int off = bl*8 + (kq ^ (bl & 7));
        bH[g] = sB[buf][0][off];
        bL[g] = sB[buf][1][off];
      }
      #pragma unroll
      for (int g = 0; g < 3; ++g)
        #pragma unroll
        for (int rt = 0; rt < 2; ++rt){
          accH[g][rt] = __builtin_amdgcn_mfma_f32_16x16x32_f16(aH[rt], bH[g], accH[g][rt], 0,0,0);
          accX[g][rt] = __builtin_amdgcn_mfma_f32_16x16x32_f16(aH[rt], bL[g], accX[g][rt], 0,0,0);
          accX[g][rt] = __builtin_amdgcn_mfma_f32_16x16x32_f16(aL[rt], bH[g], accX[g][rt], 0,0,0);
        }
    }
    if (ck < 15){
      SWRITE(buf^1);            // safe: buf^1 fully consumed before last barrier
      if (ck < 14) GLOAD(ck+2); // 2-chunk-ahead prefetch
    }
    __syncthreads();
  }
#undef GLOAD
#undef SWRITE

  const float s = 1.0f/2048.0f;
  const int col = colBlk*64 + cbase + lid;
  #pragma unroll
  for (int rt = 0; rt < 2; ++rt){
    #pragma unroll
    for (int r = 0; r < 4; ++r){
      int row = rowBlk*64 + rbase + rt*16 + quad*4 + r;
      int tk;
      if (DEC) tk = (t == 0) ? 0 : (255 - (int)(tokPrev[row] & 255));
      else     tk = x[(size_t)row*256 + t] & 255;
      const float* trow = table + (size_t)tk*3072;
      float Cr = accH[0][rt][r] + accX[0][rt][r]*s + bhh[col];
      float Cz = accH[1][rt][r] + accX[1][rt][r]*s + bhh[1024+col];
      float Cn = accH[2][rt][r] + accX[2][rt][r]*s + bhh[2048+col];
      float rg = sigm(trow[col] + Cr);
      float zg = sigm(trow[1024+col] + Cz);
      float ng = tanhf(trow[2048+col] + rg*Cn);
      size_t o = (size_t)row*1024 + col;
      float hv = (1.0f - zg)*ng + zg*hOldF[o];
      hNewF[o] = hv;
      f16 hi = (f16)hv;
      float rr2 = hv - (float)hi;
      hNewHi[o] = hi;
      hNewLo[o] = (f16)(rr2 * 2048.0f);
    }
  }
}

// ---------------- logits: 256 blocks x (16 rows x 64 cols); packed-u64 atomic argmax --------
// key = (order-preserving-u32(value) << 8) | (255 - col): max => max value, lowest col on ties
__device__ __forceinline__ u64 akey(float v, int gcol){
  unsigned int b = __float_as_uint(v);
  unsigned int u = (b & 0x80000000u) ? ~b : (b | 0x80000000u);
  return ((u64)u << 8) | (unsigned)(255 - gcol);
}

__global__ __launch_bounds__(256) void logits_argmax(
    const f16* __restrict__ hHi, const f16* __restrict__ hLo,
    const f16* __restrict__ oWHi, const f16* __restrict__ oWLo,
    const float* __restrict__ outB,
    float* __restrict__ outRecon, int t,
    u64* __restrict__ tokCur, u64* __restrict__ tokNext)
{
  __shared__ float lds[16][64];
  const int lane = threadIdx.x & 63;
  const int wave = threadIdx.x >> 6;
  const int quad = lane >> 4, lid = lane & 15;
  const int rowBase = (blockIdx.x >> 2) * 16;
  const int cgrp = blockIdx.x & 3;
  if (cgrp == 0 && threadIdx.x < 16) tokNext[rowBase + threadIdx.x] = 0ull; // reset t+1 buffer
  const int colBase = cgrp*64 + wave*16;

  f32x4 accH = {}, accX = {};
  for (int k0 = 0; k0 < 1024; k0 += 32){
    size_t aoff = (size_t)(rowBase + lid)*1024 + k0 + quad*8;
    f16x8 aH = *(const f16x8*)(hHi + aoff);
    f16x8 aL = *(const f16x8*)(hLo + aoff);
    size_t boff = (size_t)(colBase + lid)*1024 + k0 + quad*8;
    f16x8 bH = *(const f16x8*)(oWHi + boff);
    f16x8 bL = *(const f16x8*)(oWLo + boff);
    accH = __builtin_amdgcn_mfma_f32_16x16x32_f16(aH, bH, accH, 0,0,0);
    accX = __builtin_amdgcn_mfma_f32_16x16x32_f16(aH, bL, accX, 0,0,0);
    accX = __builtin_amdgcn_mfma_f32_16x16x32_f16(aL, bH, accX, 0,0,0);
  }
  const float sc = 1.0f/2048.0f;
  const int col = colBase + lid;
  #pragma unroll
  for (int r = 0; r < 4; ++r){
    int rl = quad*4 + r;
    float v = accH[r] + accX[r]*sc + outB[col];
    lds[rl][col - cgrp*64] = v;
    outRecon[(size_t)(rowBase + rl)*65536 + (size_t)t*256 + col] = v;
  }
  __syncthreads();
  // wave w reduces rows w*4..w*4+3 over this block's 64 cols, then one atomic per row
  #pragma unroll
  for (int rr = 0; rr < 4; ++rr){
    int rl = wave*4 + rr;
    u64 k = akey(lds[rl][lane], cgrp*64 + lane);
    for (int off = 32; off >= 1; off >>= 1){
      u64 o = __shfl_down(k, off, 64);
      if (o > k) k = o;
    }
    if (lane == 0) atomicMax(tokCur + rowBase + rl, k);
  }
}

// ---------------- latent A: mu, logvar, z ----------------
__global__ __launch_bounds__(256) void latent_a(
    const float* __restrict__ hT,
    const float* __restrict__ muW, const float* __restrict__ muB,
    const float* __restrict__ lvW, const float* __restrict__ lvB,
    const float* __restrict__ eps,
    float* __restrict__ outMu, float* __restrict__ outLv,
    float* __restrict__ z)
{
  __shared__ float sh[1024];
  int b = blockIdx.x, l = threadIdx.x;
  for (int i = l; i < 1024; i += 256) sh[i] = hT[(size_t)b*1024 + i];
  __syncthreads();
  const float* mw = muW + (size_t)l*1024;
  const float* lw = lvW + (size_t)l*1024;
  float sm = 0.f, sv = 0.f;
  #pragma unroll 8
  for (int k = 0; k < 1024; ++k){ float h = sh[k]; sm += h*mw[k]; sv += h*lw[k]; }
  sm += muB[l]; sv += lvB[l];
  float zz = sm + eps[(size_t)b*256 + l] * expf(0.5f*sv);
  outMu[(size_t)b*256 + l] = sm;
  outLv[(size_t)b*256 + l] = sv;
  z[(size_t)b*256 + l] = zz;
}

// ---------------- latent B: h0_dec = tanh(z @ l2h^T + b) ----------------
__global__ __launch_bounds__(256) void latent_b(
    const float* __restrict__ z,
    const float* __restrict__ l2hW, const float* __restrict__ l2hB,
    float* __restrict__ hF, f16* __restrict__ hHi, f16* __restrict__ hLo)
{
  __shared__ float sz[256];
  int b = blockIdx.x;
  int jj = blockIdx.y*256 + threadIdx.x;
  sz[threadIdx.x] = z[(size_t)b*256 + threadIdx.x];
  __syncthreads();
  const float* wr = l2hW + (size_t)jj*256;
  float s = 0.f;
  #pragma unroll 8
  for (int k = 0; k < 256; ++k) s += sz[k]*wr[k];
  float h = tanhf(s + l2hB[jj]);
  size_t o = (size_t)b*1024 + jj;
  hF[o] = h;
  f16 hi = (f16)h;
  float r = h - (float)hi;
  hHi[o] = hi;
  hLo[o] = (f16)(r * 2048.0f);
}

extern "C" void kernel_launch(void* const* d_in, const int* in_sizes, int n_in,
                              void* d_out, int out_size, void* d_ws, size_t ws_size,
                              hipStream_t stream) {
  const int*   x      = (const int*)d_in[0];
  const float* eps    = (const float*)d_in[1];
  const float* emb    = (const float*)d_in[2];
  const float* encWih = (const float*)d_in[3];
  const float* encWhh = (const float*)d_in[4];
  const float* encBih = (const float*)d_in[5];
  const float* encBhh = (const float*)d_in[6];
  const float* muW    = (const float*)d_in[7];
  const float* muB    = (const float*)d_in[8];
  const float* lvW    = (const float*)d_in[9];
  const float* lvB    = (const float*)d_in[10];
  const float* l2hW   = (const float*)d_in[11];
  const float* l2hB   = (const float*)d_in[12];
  const float* decWih = (const float*)d_in[13];
  const float* decWhh = (const float*)d_in[14];
  const float* decBih = (const float*)d_in[15];
  const float* decBhh = (const float*)d_in[16];
  const float* outW   = (const float*)d_in[17];
  const float* outB   = (const float*)d_in[18];

  // ---- outputs (fp32) ----
  float* outRecon = (float*)d_out;               // [1024][256][256]
  float* outMu    = outRecon + 67108864;         // [1024][256]
  float* outLv    = outMu + 262144;

  // ---- encoder-phase scratch inside d_out recon region (dead until decode) ----
  char* ob = (char*)d_out;
  float* tabE   = (float*)(ob + 0);              // 3 MB
  f16*   eWHi   = (f16*)(ob + 3145728);          // 6 MB
  f16*   eWLo   = (f16*)(ob + 9437184);          // 6 MB
  float* zbuf   = (float*)(ob + 15728640);       // 1 MB

  // ---- decoder-persistent scratch in ws ----
  char* ws = (char*)d_ws;
  float* tabD   = (float*)(ws + 0);              // 3 MB
  f16*   dWHi   = (f16*)(ws + 3145728);          // 6 MB
  f16*   dWLo   = (f16*)(ws + 9437184);          // 6 MB
  f16*   oWHi   = (f16*)(ws + 15728640);         // 0.5 MB
  f16*   oWLo   = (f16*)(ws + 16252928);         // 0.5 MB
  float* hF[2]  = { (float*)(ws + 16777216), (float*)(ws + 25165824) };
  f16*   hHi[2] = { (f16*)(ws + 20971520),   (f16*)(ws + 29360128) };
  f16*   hLo[2] = { (f16*)(ws + 23068672),   (f16*)(ws + 31457280) };
  u64*   tokb[2]= { (u64*)(ws + 33554432),   (u64*)(ws + 33562624) };  // 8 KB each

  // weight limb splits
  split_w<<<12288, 256, 0, stream>>>(encWhh, eWHi, eWLo, 3145728);
  split_w<<<12288, 256, 0, stream>>>(decWhh, dWHi, dWLo, 3145728);
  split_w<<<1024, 256, 0, stream>>>(outW, oWHi, oWLo, 262144);

  // token->gi tables (fp32)
  build_tables<<<dim3(12,256,2), 256, 0, stream>>>(emb, encWih, encBih, decWih, decBih, tabE, tabD);

  // zero encoder h0 (hF0 + hHi0 + hLo0 contiguous, 8 MB) and token argmax buffers
  hipMemsetAsync(ws + 16777216, 0, 8388608, stream);
  hipMemsetAsync(ws + 33554432, 0, 16384, stream);

  // ---- encoder: 256 GRU steps, ping-pong ----
  for (int t = 0; t < 256; ++t){
    int a = t & 1, b = a ^ 1;
    gru_kernel<0><<<256, 512, 0, stream>>>(
        hHi[a], hLo[a], hF[a], eWHi, eWLo, encBhh, tabE, x, nullptr, t,
        hF[b], hHi[b], hLo[b]);
  }
  // hT in buffer 0

  // ---- latent ----
  latent_a<<<1024, 256, 0, stream>>>(hF[0], muW, muB, lvW, lvB, eps, outMu, outLv, zbuf);
  latent_b<<<dim3(1024,4), 256, 0, stream>>>(zbuf, l2hW, l2hB, hF[0], hHi[0], hLo[0]);

  // ---- decoder: 256 x (GRU step + logits/argmax) ----
  for (int t = 0; t < 256; ++t){
    int a = t & 1, b = a ^ 1;
    gru_kernel<1><<<256, 512, 0, stream>>>(
        hHi[a], hLo[a], hF[a], dWHi, dWLo, decBhh, tabD, nullptr, tokb[(t+1)&1], t,
        hF[b], hHi[b], hLo[b]);
    logits_argmax<<<256, 256, 0, stream>>>(
        hHi[b], hLo[b], oWHi, oWLo, outB, outRecon, t, tokb[t&1], tokb[(t+1)&1]);
  }
  (void)in_sizes; (void)n_in; (void)out_size; (void)ws_size;
}